// Round 2
// baseline (5933.578 us; speedup 1.0000x reference)
//
#include <hip/hip_runtime.h>

// ---------------------------------------------------------------------------
// Generalized direct 3x3 SAME conv + ReLU, fp32, row-range aware.
//
// Input buffer holds rows [in_y0, in_y0+in_rows) of the image (in_y0=0,
// in_rows=H for a full image). Output buffer receives rows
// [out_y0, out_y0+out_rows). Sampling outside the buffer's row range or
// outside [0,W) columns yields zero — by construction the strip buffers
// always contain every in-image row a consumer needs, so this matches
// SAME zero-padding exactly.
//
// Block: 256 threads = 16x16 output tile, CB output channels per block
// (accumulators in VGPRs). Per input channel: stage 18x18 halo tile in
// LDS, read 9 taps into regs, then CB*9 FMAs with scalar-uniform weight
// loads (s_load -> v_fmac with SGPR operand).
// ---------------------------------------------------------------------------
template<int CIN, int COUT, int CB>
__global__ __launch_bounds__(256) void conv3x3_relu_k(
    const float* __restrict__ in, const float* __restrict__ wt,
    float* __restrict__ out,
    int W, int in_y0, int in_rows, int out_y0, int out_rows)
{
  constexpr int NCB = (COUT + CB - 1) / CB;
  const int n   = blockIdx.z / NCB;            // image index (encoder path)
  const int co0 = (blockIdx.z % NCB) * CB;
  const int tx = threadIdx.x & 15, ty = threadIdx.x >> 4;
  const int x0 = blockIdx.x * 16;
  const int oy0 = out_y0 + blockIdx.y * 16;    // image row of tile top
  const int x = x0 + tx;

  __shared__ float tile[18][19];               // +1 pad col vs banks

  float acc[CB];
#pragma unroll
  for (int j = 0; j < CB; ++j) acc[j] = 0.f;

  const float* inN = in + (size_t)n * CIN * in_rows * W;

  for (int ci = 0; ci < CIN; ++ci) {
    const float* ip = inN + (size_t)ci * in_rows * W;
    // stage 18x18 halo tile; zero outside buffer rows / image cols
    for (int t = threadIdx.x; t < 18 * 18; t += 256) {
      int r = t / 18, c = t - r * 18;
      int yi = oy0 + r - 1 - in_y0;            // buffer-relative row
      int xi = x0 + c - 1;
      float v = 0.f;
      if (yi >= 0 && yi < in_rows && xi >= 0 && xi < W)
        v = ip[(size_t)yi * W + xi];
      tile[r][c] = v;
    }
    __syncthreads();

    const float p0 = tile[ty + 0][tx + 0], p1 = tile[ty + 0][tx + 1], p2 = tile[ty + 0][tx + 2];
    const float p3 = tile[ty + 1][tx + 0], p4 = tile[ty + 1][tx + 1], p5 = tile[ty + 1][tx + 2];
    const float p6 = tile[ty + 2][tx + 0], p7 = tile[ty + 2][tx + 1], p8 = tile[ty + 2][tx + 2];

#pragma unroll
    for (int j = 0; j < CB; ++j) {
      int co = co0 + j;
      if (co >= COUT) co = COUT - 1;           // clamp: loads stay in-bounds, result unused
      const float* wp = wt + ((size_t)co * CIN + ci) * 9;  // wave-uniform -> s_load
      float a = acc[j];
      a = fmaf(p0, wp[0], a); a = fmaf(p1, wp[1], a); a = fmaf(p2, wp[2], a);
      a = fmaf(p3, wp[3], a); a = fmaf(p4, wp[4], a); a = fmaf(p5, wp[5], a);
      a = fmaf(p6, wp[6], a); a = fmaf(p7, wp[7], a); a = fmaf(p8, wp[8], a);
      acc[j] = a;
    }
    __syncthreads();
  }

  const int orow = (oy0 + ty) - out_y0;
  float* outN = out + (size_t)n * COUT * out_rows * W;
  if (orow < out_rows) {
#pragma unroll
    for (int j = 0; j < CB; ++j) {
      int co = co0 + j;
      if (co < COUT) {
        float v = acc[j] < 0.f ? 0.f : acc[j];
        outN[((size_t)co * out_rows + orow) * W + x] = v;
      }
    }
  }
}

// ---------------------------------------------------------------------------
// PixelShuffle r=4 + ReLU for ONE image: (16,256,256) -> (1024,1024)
// out[4*hh+ii, 4*ww+jj] = in[ii*4+jj, hh, ww]
// ---------------------------------------------------------------------------
__global__ __launch_bounds__(256) void pixel_shuffle_relu_k(
    const float* __restrict__ in, float* __restrict__ out)
{
  int i = blockIdx.x * 256 + threadIdx.x;      // over 1024*1024
  int x = i & 1023, y = i >> 10;
  int c = (y & 3) * 4 + (x & 3);
  float v = in[((size_t)c * 256 + (y >> 2)) * 256 + (x >> 2)];
  out[i] = v < 0.f ? 0.f : v;
}

// ---------------------------------------------------------------------------
// Per-pixel 5x5 dynamic conv + residual, one image, one row-strip:
// out[y,x] = h[y,x] + sum_{kw,kh} h_pad[y+kh-2, x+kw-2] * ker[kw*5+kh, y, x]
// ker holds rows [ky0, ky0+krows) of the image (channel stride krows*1024).
// ---------------------------------------------------------------------------
__global__ __launch_bounds__(256) void pixel_conv_add_k(
    const float* __restrict__ h,    // full image (1024,1024)
    const float* __restrict__ ker,  // (25, krows, 1024)
    float* __restrict__ out,        // full image (1024,1024)
    int ky0, int krows)
{
  const int tx = threadIdx.x & 15, ty = threadIdx.x >> 4;
  const int x0 = blockIdx.x * 16;
  const int y0 = ky0 + blockIdx.y * 16;

  __shared__ float tile[20][21];
  for (int t = threadIdx.x; t < 20 * 20; t += 256) {
    int r = t / 20, c = t - r * 20;
    int yy = y0 + r - 2, xx = x0 + c - 2;
    float v = 0.f;
    if (yy >= 0 && yy < 1024 && xx >= 0 && xx < 1024) v = h[(size_t)yy * 1024 + xx];
    tile[r][c] = v;
  }
  __syncthreads();

  const int x = x0 + tx, y = y0 + ty;
  float acc = tile[ty + 2][tx + 2];            // residual h
  const size_t kpix = (size_t)(y - ky0) * 1024 + x;
#pragma unroll
  for (int kw = 0; kw < 5; ++kw) {
#pragma unroll
    for (int kh = 0; kh < 5; ++kh) {
      float kv = ker[(size_t)(kw * 5 + kh) * krows * 1024 + kpix];
      acc = fmaf(tile[ty + kh][tx + kw], kv, acc);
    }
  }
  out[(size_t)y * 1024 + x] = acc;
}

// ---------------------------------------------------------------------------
// Launch. Workspace (adaptive to ws_size):
//   Hs: 8 MiB  — shuffled h, both images, persists
//   A : max(32ch*(S+6)*1024*4, 8.4 MB)   — z1/z3 strip buf; encoder ping
//   B : max(64ch*(S+4)*1024*4, 16.8 MB)  — z2/z4 strip buf; encoder pong
// S = largest of {1024,512,256,128,64} fitting ws_size (min config ~33.5 MB).
// z-branch runs in row strips of height S with halo-recompute (identical
// numerics to full-image conv).
// ---------------------------------------------------------------------------
extern "C" void kernel_launch(void* const* d_in, const int* in_sizes, int n_in,
                              void* d_out, int out_size, void* d_ws, size_t ws_size,
                              hipStream_t stream) {
  const float* x    = (const float*)d_in[0];
  const float* w_e1 = (const float*)d_in[1];
  const float* w_e2 = (const float*)d_in[2];
  const float* w_e3 = (const float*)d_in[3];
  const float* w_d1 = (const float*)d_in[4];
  const float* w_d2 = (const float*)d_in[5];
  const float* w_k1 = (const float*)d_in[6];
  const float* w_k2 = (const float*)d_in[7];
  const float* w_k3 = (const float*)d_in[8];
  const float* w_k4 = (const float*)d_in[9];

  const size_t HS_SZ = 8388608;                 // 2 * 1024*1024 * 4
  const size_t AMIN  = 8388608;                 // 32ch @256², one image
  const size_t BMIN  = 16777216;                // 64ch @256², one image

  int S = 64;
  {
    const int cand[5] = {1024, 512, 256, 128, 64};
    for (int i = 0; i < 5; ++i) {
      int s = cand[i];
      size_t a = 32ull * (size_t)(s + 6) * 1024 * 4; if (a < AMIN) a = AMIN;
      size_t b = 64ull * (size_t)(s + 4) * 1024 * 4; if (b < BMIN) b = BMIN;
      if (HS_SZ + a + b <= ws_size) { S = s; break; }
    }
  }
  size_t A_SZ = 32ull * (size_t)(S + 6) * 1024 * 4; if (A_SZ < AMIN) A_SZ = AMIN;

  char* ws = (char*)d_ws;
  float* Hs = (float*)(ws);
  float* A  = (float*)(ws + HS_SZ);
  float* B  = (float*)(ws + HS_SZ + A_SZ);
  float* outp = (float*)d_out;

  dim3 blk(256);

  // ---- encoder/decoder @256², per image, ping-pong A<->B ----
  for (int n = 0; n < 2; ++n) {
    const float* xn = x + (size_t)n * 65536;
    conv3x3_relu_k<1, 16, 16><<<dim3(16, 16, 1), blk, 0, stream>>>(xn, w_e1, B, 256, 0, 256, 0, 256);
    conv3x3_relu_k<16, 32, 16><<<dim3(16, 16, 2), blk, 0, stream>>>(B, w_e2, A, 256, 0, 256, 0, 256);
    conv3x3_relu_k<32, 64, 16><<<dim3(16, 16, 4), blk, 0, stream>>>(A, w_e3, B, 256, 0, 256, 0, 256);
    conv3x3_relu_k<64, 32, 16><<<dim3(16, 16, 2), blk, 0, stream>>>(B, w_d1, A, 256, 0, 256, 0, 256);
    conv3x3_relu_k<32, 16, 16><<<dim3(16, 16, 1), blk, 0, stream>>>(A, w_d2, B, 256, 0, 256, 0, 256);
    pixel_shuffle_relu_k<<<dim3(4096), blk, 0, stream>>>(B, Hs + (size_t)n * 1048576);
  }

  // ---- kernel-prediction branch + dynamic conv, per image, row strips ----
  const int nstr = 1024 / S;
  for (int n = 0; n < 2; ++n) {
    const float* himg = Hs + (size_t)n * 1048576;
    float* outn = outp + (size_t)n * 1048576;
    for (int s = 0; s < nstr; ++s) {
      const int r0 = s * S, r1 = r0 + S;
      const int z1y0 = (r0 - 3 > 0) ? r0 - 3 : 0;
      const int z1r  = ((r1 + 3 < 1024) ? r1 + 3 : 1024) - z1y0;
      const int z2y0 = (r0 - 2 > 0) ? r0 - 2 : 0;
      const int z2r  = ((r1 + 2 < 1024) ? r1 + 2 : 1024) - z2y0;
      const int z3y0 = (r0 - 1 > 0) ? r0 - 1 : 0;
      const int z3r  = ((r1 + 1 < 1024) ? r1 + 1 : 1024) - z3y0;
      const int g1 = (z1r + 15) / 16, g2 = (z2r + 15) / 16, g3 = (z3r + 15) / 16;

      conv3x3_relu_k<1, 32, 16><<<dim3(64, g1, 2), blk, 0, stream>>>(
          himg, w_k1, A, 1024, 0, 1024, z1y0, z1r);
      conv3x3_relu_k<32, 64, 16><<<dim3(64, g2, 4), blk, 0, stream>>>(
          A, w_k2, B, 1024, z1y0, z1r, z2y0, z2r);
      conv3x3_relu_k<64, 32, 16><<<dim3(64, g3, 2), blk, 0, stream>>>(
          B, w_k3, A, 1024, z2y0, z2r, z3y0, z3r);
      conv3x3_relu_k<32, 25, 16><<<dim3(64, S / 16, 2), blk, 0, stream>>>(
          A, w_k4, B, 1024, z3y0, z3r, r0, S);
      pixel_conv_add_k<<<dim3(64, S / 16), blk, 0, stream>>>(
          himg, B, outn, r0, S);
    }
  }
}